// Round 2
// baseline (99.327 us; speedup 1.0000x reference)
//
#include <hip/hip_runtime.h>

// ---------- types ----------
typedef _Float16 v8h __attribute__((ext_vector_type(8)));
typedef float    v4f __attribute__((ext_vector_type(4)));

// ---------- helpers ----------
__device__ __forceinline__ void gl_lds16(const void* g, void* l) {
  __builtin_amdgcn_global_load_lds(
      (__attribute__((address_space(1))) void*)(void*)g,
      (__attribute__((address_space(3))) void*)l, 16, 0, 0);
}
__device__ __forceinline__ v8h cvt8(const float4 a, const float4 b) {
  v8h o;
  o[0] = (_Float16)a.x; o[1] = (_Float16)a.y; o[2] = (_Float16)a.z; o[3] = (_Float16)a.w;
  o[4] = (_Float16)b.x; o[5] = (_Float16)b.y; o[6] = (_Float16)b.z; o[7] = (_Float16)b.w;
  return o;
}

// ---------- conversion: both weights fp32 -> fp16 in one launch ----------
__global__ void conv_w(const float4* __restrict__ wp, const float4* __restrict__ wc,
                       v8h* __restrict__ op, v8h* __restrict__ oc) {
  const int n = 73728;  // 768*768/8
  int i = blockIdx.x * blockDim.x + threadIdx.x;
  const float4* src = (i < n) ? wp : wc;
  v8h* dst = (i < n) ? op : oc;
  const int j = (i < n) ? i : i - n;
  dst[j] = cvt8(src[2 * j], src[2 * j + 1]);
}

// ============================================================================
// GEMM structure: BM=BN=64, BK=64, 12 K-iters, 4 waves, 2x2 of 16x16x32_f16.
// Minimum 2-phase pipeline (catalog T3-minimum), __syncthreads()-only sync:
//  - BOTH A and B double-buffered in LDS (4 x 8KB = 32KB)
//  - per iter: STAGE tile k+1 into buf^1 FIRST, then MFMA on buf, then ONE
//    __syncthreads(). The vmcnt(0) drain inside __syncthreads now waits on
//    loads issued a full MFMA phase earlier instead of just-issued ones.
//  - gemm1's A (fp32 X) is reg-staged two levels deep: ds_write A(k+1) from
//    registers loaded LAST iteration (already drained by the last barrier,
//    so the write never stalls), then load X(k+2).
// LDS XOR-swizzle: 8 col-groups of 8 fp16 per 64-col row, phys = logical ^
// (row&7); applied on the pre-swizzled GLOBAL source at staging and on the
// fragment-read index (both-sides-or-neither). Staging LDS dest stays linear
// (gl_lds wave-uniform + lane*16 requirement).
// Grid 64x12=768 blocks (3/CU, all co-resident), XCD swizzle unchanged.
// ============================================================================

// ---------- GEMM1 + quantum head, fused ----------
__global__ __launch_bounds__(256) void gemm1_qh(
    const float* __restrict__ X,          // [4096][768] fp32
    const _Float16* __restrict__ B,       // [768][768] fp16 (W_proj)
    const float* __restrict__ bp,         // [768]
    const float* __restrict__ theta,      // [8]
    _Float16* __restrict__ EZ) {          // [4096][768] fp16
  const int t = threadIdx.x;
  const int b = blockIdx.x;
  const int xcd = b & 7, slot = b >> 3;
  const int bm = xcd * 8 + slot / 12;
  const int bn = slot % 12;

  const int wave = t >> 6, lane = t & 63;
  const int quad = lane >> 4, l16 = lane & 15;
  const int wm = (wave >> 1) * 32, wn = (wave & 1) * 32;

  __shared__ __align__(16) unsigned char smem[32768];
  // A buffers at 0 / 8192, B buffers at 16384 / 24576 (each 64x64 fp16 = 8KB)
  float* Cs = (float*)smem;  // epilogue reuse: 64 x 68 fp32 (17408B)

  const float4 th0 = *(const float4*)theta;
  const float4 th1 = *(const float4*)(theta + 4);

  // staging decomposition: thread t -> row r (0..31 per 32-row chunk), phys
  // col-group cg (0..7, 16B units); source logical col-group = cg ^ (r&7)
  const int r = t >> 3;
  const int cg = t & 7;
  const int lcg = cg ^ (r & 7);

  const float*    Xg = X + (size_t)(bm * 64 + r) * 768 + lcg * 8;
  const _Float16* Bg = B + (size_t)(bn * 64 + r) * 768 + lcg * 8;

  v4f acc[2][2];
#pragma unroll
  for (int i = 0; i < 2; i++)
#pragma unroll
    for (int j = 0; j < 2; j++) acc[i][j] = (v4f){0.f, 0.f, 0.f, 0.f};

  // ---- prologue: stage tile 0 into buffer 0, prefetch X(1) into regs ----
  float4 xr[4];
#pragma unroll
  for (int c = 0; c < 2; c++) {
    const float* p = Xg + (size_t)c * 32 * 768;
    xr[2 * c]     = *(const float4*)p;
    xr[2 * c + 1] = *(const float4*)(p + 4);
  }
  {
    _Float16* B0 = (_Float16*)(smem + 16384);
    gl_lds16(Bg, &B0[t * 8]);
    gl_lds16(Bg + (size_t)32 * 768, &B0[2048 + t * 8]);
    _Float16* A0 = (_Float16*)smem;
    *(v8h*)&A0[t * 8]        = cvt8(xr[0], xr[1]);
    *(v8h*)&A0[2048 + t * 8] = cvt8(xr[2], xr[3]);
  }
#pragma unroll
  for (int c = 0; c < 2; c++) {
    const float* p = Xg + (size_t)c * 32 * 768 + 64;
    xr[2 * c]     = *(const float4*)p;
    xr[2 * c + 1] = *(const float4*)(p + 4);
  }
  __syncthreads();

  // ---- main loop: stage k+1 first, then MFMA on k, one barrier ----
#pragma unroll
  for (int it = 0; it < 12; ++it) {
    _Float16* Ac = (_Float16*)(smem + (it & 1) * 8192);
    _Float16* Bc = (_Float16*)(smem + 16384 + (it & 1) * 8192);
    if (it < 11) {
      _Float16* An = (_Float16*)(smem + ((it + 1) & 1) * 8192);
      _Float16* Bn = (_Float16*)(smem + 16384 + ((it + 1) & 1) * 8192);
      const int kn = (it + 1) * 64;
      gl_lds16(Bg + kn, &Bn[t * 8]);
      gl_lds16(Bg + (size_t)32 * 768 + kn, &Bn[2048 + t * 8]);
      // A(k+1) from regs loaded last iteration (already drained at last bar)
      *(v8h*)&An[t * 8]        = cvt8(xr[0], xr[1]);
      *(v8h*)&An[2048 + t * 8] = cvt8(xr[2], xr[3]);
      if (it < 10) {
        const int kf = (it + 2) * 64;
#pragma unroll
        for (int c = 0; c < 2; c++) {
          const float* p = Xg + (size_t)c * 32 * 768 + kf;
          xr[2 * c]     = *(const float4*)p;
          xr[2 * c + 1] = *(const float4*)(p + 4);
        }
      }
    }
#pragma unroll
    for (int q = 0; q < 2; q++) {
      v8h af[2], bf[2];
#pragma unroll
      for (int i = 0; i < 2; i++)
        af[i] = *(const v8h*)&Ac[(wm + i * 16 + l16) * 64 + ((((q << 2) + quad) ^ (l16 & 7)) << 3)];
#pragma unroll
      for (int j = 0; j < 2; j++)
        bf[j] = *(const v8h*)&Bc[(wn + j * 16 + l16) * 64 + ((((q << 2) + quad) ^ (l16 & 7)) << 3)];
#pragma unroll
      for (int i = 0; i < 2; i++)
#pragma unroll
        for (int j = 0; j < 2; j++)
          acc[i][j] = __builtin_amdgcn_mfma_f32_16x16x32_f16(af[i], bf[j], acc[i][j], 0, 0, 0);
    }
    __syncthreads();
  }

  // ---- epilogue: acc -> LDS (stride 68), then quantum head per row-head ----
  const int r0 = wm + quad * 4;
  const int c0 = wn + l16;
#pragma unroll
  for (int j = 0; j < 2; j++)
#pragma unroll
    for (int i = 0; i < 2; i++)
#pragma unroll
      for (int rr = 0; rr < 4; rr++)
        Cs[(r0 + i * 16 + rr) * 68 + c0 + j * 16] = acc[i][j][rr];
  __syncthreads();

#pragma unroll
  for (int s = 0; s < 2; s++) {
    const int idx = t + s * 256;          // 0..511 = 64 rows x 8 heads
    const int row = idx >> 3, h = idx & 7;
    const int gcol = bn * 64 + h * 8;
    const float* cr = &Cs[row * 68 + h * 8];
    const float4 q0 = *(const float4*)cr;
    const float4 q1 = *(const float4*)(cr + 4);
    const float4 b0 = *(const float4*)(bp + gcol);
    const float4 b1 = *(const float4*)(bp + gcol + 4);
    float c[8];
    c[0] = cosf(q0.x + b0.x + th0.x);
    c[1] = cosf(q0.y + b0.y + th0.y);
    c[2] = cosf(q0.z + b0.z + th0.z);
    c[3] = cosf(q0.w + b0.w + th0.w);
    c[4] = cosf(q1.x + b1.x + th1.x);
    c[5] = cosf(q1.y + b1.y + th1.y);
    c[6] = cosf(q1.z + b1.z + th1.z);
    c[7] = cosf(q1.w + b1.w + th1.w);
    float e[8];
    e[0] = c[1] * c[2] * c[3] * c[4] * c[5] * c[6] * c[7];
    float pr = c[0];
#pragma unroll
    for (int w = 1; w < 8; w++) { pr *= c[w]; e[w] = pr; }
    v8h ov;
#pragma unroll
    for (int w = 0; w < 8; w++) ov[w] = (_Float16)e[w];
    *(v8h*)(EZ + (size_t)(bm * 64 + row) * 768 + gcol) = ov;
  }
}

// ---------- GEMM2: out = EZ @ Wc^T + bc, fp16 in, fp32 out ----------
__global__ __launch_bounds__(256) void gemm2(
    const _Float16* __restrict__ A,       // [4096][768] fp16 (EZ)
    const _Float16* __restrict__ B,       // [768][768] fp16 (W_comb)
    float* __restrict__ C,                // [4096][768] fp32
    const float* __restrict__ bias) {
  const int t = threadIdx.x;
  const int b = blockIdx.x;
  const int xcd = b & 7, slot = b >> 3;
  const int bm = xcd * 8 + slot / 12;
  const int bn = slot % 12;

  const int wave = t >> 6, lane = t & 63;
  const int quad = lane >> 4, l16 = lane & 15;
  const int wm = (wave >> 1) * 32, wn = (wave & 1) * 32;

  __shared__ __align__(16) unsigned char smem[32768];

  const int r = t >> 3;
  const int cg = t & 7;
  const int lcg = cg ^ (r & 7);

  const _Float16* Ag = A + (size_t)(bm * 64 + r) * 768 + lcg * 8;
  const _Float16* Bg = B + (size_t)(bn * 64 + r) * 768 + lcg * 8;

  v4f acc[2][2];
#pragma unroll
  for (int i = 0; i < 2; i++)
#pragma unroll
    for (int j = 0; j < 2; j++) acc[i][j] = (v4f){0.f, 0.f, 0.f, 0.f};

  // ---- prologue: stage tile 0 into buffer 0 ----
  {
    _Float16* A0 = (_Float16*)smem;
    _Float16* B0 = (_Float16*)(smem + 16384);
    gl_lds16(Ag, &A0[t * 8]);
    gl_lds16(Ag + (size_t)32 * 768, &A0[2048 + t * 8]);
    gl_lds16(Bg, &B0[t * 8]);
    gl_lds16(Bg + (size_t)32 * 768, &B0[2048 + t * 8]);
  }
  __syncthreads();

  // ---- main loop: pure gl_lds double-buffered prefetch ----
#pragma unroll
  for (int it = 0; it < 12; ++it) {
    _Float16* Ac = (_Float16*)(smem + (it & 1) * 8192);
    _Float16* Bc = (_Float16*)(smem + 16384 + (it & 1) * 8192);
    if (it < 11) {
      _Float16* An = (_Float16*)(smem + ((it + 1) & 1) * 8192);
      _Float16* Bn = (_Float16*)(smem + 16384 + ((it + 1) & 1) * 8192);
      const int kn = (it + 1) * 64;
      gl_lds16(Ag + kn, &An[t * 8]);
      gl_lds16(Ag + (size_t)32 * 768 + kn, &An[2048 + t * 8]);
      gl_lds16(Bg + kn, &Bn[t * 8]);
      gl_lds16(Bg + (size_t)32 * 768 + kn, &Bn[2048 + t * 8]);
    }
#pragma unroll
    for (int q = 0; q < 2; q++) {
      v8h af[2], bf[2];
#pragma unroll
      for (int i = 0; i < 2; i++)
        af[i] = *(const v8h*)&Ac[(wm + i * 16 + l16) * 64 + ((((q << 2) + quad) ^ (l16 & 7)) << 3)];
#pragma unroll
      for (int j = 0; j < 2; j++)
        bf[j] = *(const v8h*)&Bc[(wn + j * 16 + l16) * 64 + ((((q << 2) + quad) ^ (l16 & 7)) << 3)];
#pragma unroll
      for (int ii = 0; ii < 2; ii++)
#pragma unroll
        for (int j = 0; j < 2; j++)
          acc[ii][j] = __builtin_amdgcn_mfma_f32_16x16x32_f16(af[ii], bf[j], acc[ii][j], 0, 0, 0);
    }
    __syncthreads();
  }

  const int row0 = bm * 64 + wm + quad * 4;
  const int col0 = bn * 64 + wn + l16;
#pragma unroll
  for (int j = 0; j < 2; j++) {
    const int col = col0 + j * 16;
    const float bv = bias[col];
#pragma unroll
    for (int i = 0; i < 2; i++) {
#pragma unroll
      for (int rr = 0; rr < 4; rr++) {
        C[(size_t)(row0 + i * 16 + rr) * 768 + col] = acc[i][j][rr] + bv;
      }
    }
  }
}

// ---------- launch ----------
extern "C" void kernel_launch(void* const* d_in, const int* in_sizes, int n_in,
                              void* d_out, int out_size, void* d_ws, size_t ws_size,
                              hipStream_t stream) {
  const float* x     = (const float*)d_in[0];
  const float* Wp    = (const float*)d_in[1];
  const float* bp    = (const float*)d_in[2];
  const float* theta = (const float*)d_in[3];
  const float* Wcf   = (const float*)d_in[4];
  const float* bc    = (const float*)d_in[5];
  float* out = (float*)d_out;

  const size_t EE = (size_t)768 * 768;

  _Float16* WPH = (_Float16*)d_ws;        // [768][768] fp16 W_proj
  _Float16* WCH = WPH + EE;               // [768][768] fp16 W_comb
  _Float16* EZ  = WCH + EE;               // [4096][768] fp16 expz

  // both weight conversions in one launch
  conv_w<<<(int)(2 * EE / 8 / 256), 256, 0, stream>>>(
      (const float4*)Wp, (const float4*)Wcf, (v8h*)WPH, (v8h*)WCH);

  // GEMM1 fused with quantum head: x(fp32) @ Wp^T -> angles -> expz (fp16)
  gemm1_qh<<<768, 256, 0, stream>>>(x, WPH, bp, theta, EZ);

  // GEMM2: out = expz @ Wc^T + bc
  gemm2<<<768, 256, 0, stream>>>(EZ, WCH, out, bc);
}